// Round 6
// baseline (353.261 us; speedup 1.0000x reference)
//
#include <hip/hip_runtime.h>

#define NN  512
#define DD  128

typedef __attribute__((ext_vector_type(4))) float f32x4;
typedef __attribute__((ext_vector_type(8))) short s16x8;   // 8 bf16 (4 VGPRs)

#define MFMA(a, b, c) __builtin_amdgcn_mfma_f32_16x16x32_bf16((a), (b), (c), 0, 0, 0)

#define H1S 68    // h1 row stride (floats): 64+4 pad -> worst 2-way conflict (free)

// fp32 -> (bf16 hi [RNA], bf16 lo [trunc of exact remainder]), packed via v_perm.
// hh+hl+lh passes capture the product to ~2^-17 rel (ll term <= 2^-18, dropped).
__device__ inline void split8(const float* __restrict__ x, s16x8& h, s16x8& l) {
    uint4 hp, lp;
    unsigned* hw = (unsigned*)&hp;
    unsigned* lw = (unsigned*)&lp;
    #pragma unroll
    for (int i = 0; i < 4; ++i) {
        float x0 = x[2 * i], x1 = x[2 * i + 1];
        unsigned t0 = __float_as_uint(x0) + 0x8000u;
        unsigned t1 = __float_as_uint(x1) + 0x8000u;
        hw[i] = __builtin_amdgcn_perm(t1, t0, 0x07060302u);
        float l0 = x0 - __uint_as_float(t0 & 0xFFFF0000u);
        float l1 = x1 - __uint_as_float(t1 & 0xFFFF0000u);
        lw[i] = __builtin_amdgcn_perm(__float_as_uint(l1), __float_as_uint(l0), 0x07060302u);
    }
    h = __builtin_bit_cast(s16x8, hp);
    l = __builtin_bit_cast(s16x8, lp);
}

// 3 waves/EU PINNED (min=max): allocator budgets 512/3 = 170 VGPR.
// r5 lesson: __launch_bounds__(,3) alone let the compiler target 6 waves/EU
// (84 VGPR) and spill everything -> 624 MB scratch reads.
__global__ __launch_bounds__(256)
__attribute__((amdgpu_waves_per_eu(3, 3)))
void adj_mfma4(const float* __restrict__ v,
               const float* __restrict__ W1,
               const float* __restrict__ b1,
               const float* __restrict__ W2,
               const float* __restrict__ b2,
               const float* __restrict__ W3,
               const float* __restrict__ b3,
               float* __restrict__ out)
{
    // ~52.8 KB -> 3 blocks/CU.  B1_s is FRAG-MAJOR: frag f=kt*4+ot (hi) or
    // 16+f (lo); lane l's s16x8 at (slot*64 + l)*16 B.  Reads: one shared
    // v-addr (l*16) + immediate offsets; conflict-free; zero addr VALU.
    __shared__ __attribute__((aligned(16))) unsigned short B1_s[32 * 64 * 8];
    __shared__ __attribute__((aligned(16))) float h1_s[64 * H1S];
    __shared__ __attribute__((aligned(16))) float vi_s[DD];
    __shared__ float logits[NN];
    __shared__ float red[8];

    const int blk   = blockIdx.x;        // b*N + i
    const int t     = threadIdx.x;
    const int w     = t >> 6;            // wave 0..3
    const int l     = t & 63;
    const int m16   = t & 15;
    const int q     = l >> 4;
    const int q8    = q * 8;
    const int bbase = blk & ~(NN - 1);

    // ---- stage v_i (128 floats) ----
    if (t < DD / 4)
        ((float4*)vi_s)[t] = ((const float4*)(v + (size_t)blk * DD))[t];

    // ---- prologue: W1 -> frag-major split LDS (1024 frag-slots / 256 thr) ----
    #pragma unroll
    for (int e = 0; e < 4; ++e) {
        int slot = e * 256 + t;
        int f  = slot >> 6;              // frag 0..15 (kt*4+ot)
        int fl = slot & 63;              // lane within frag
        int kt = f >> 2, ot = f & 3;
        int fm = fl & 15, fq = fl >> 4;
        const float* src = W1 + (size_t)(ot * 16 + fm) * DD + kt * 32 + fq * 8;
        float x[8];
        *(float4*)&x[0] = *(const float4*)(src);
        *(float4*)&x[4] = *(const float4*)(src + 4);
        s16x8 h, lo;
        split8(x, h, lo);
        *(s16x8*)(B1_s + (size_t)(f * 64 + fl) * 8)        = h;
        *(s16x8*)(B1_s + (size_t)((16 + f) * 64 + fl) * 8) = lo;
    }

    // ---- B2 frags in registers (32 VGPRs; identical in every wave) ----
    s16x8 B2h[2][2], B2l[2][2];
    #pragma unroll
    for (int ot2 = 0; ot2 < 2; ++ot2)
        #pragma unroll
        for (int kt2 = 0; kt2 < 2; ++kt2) {
            const float* src = W2 + (size_t)(ot2 * 16 + m16) * 64 + kt2 * 32 + q8;
            float x[8];
            *(float4*)&x[0] = *(const float4*)(src);
            *(float4*)&x[4] = *(const float4*)(src + 4);
            split8(x, B2h[ot2][kt2], B2l[ot2][kt2]);
        }

    // per-lane constants
    float b1v[4];
    #pragma unroll
    for (int ot = 0; ot < 4; ++ot) b1v[ot] = b1[ot * 16 + m16];
    const float b2v0 = b2[m16];
    const float b2v1 = b2[16 + m16];
    const float w3v0 = W3[m16];
    const float w3v1 = W3[16 + m16];
    const float b3v  = b3[0];

    __syncthreads();   // B1 frags + vi ready

    // shared LDS read base for all B1 frag reads (imm offsets select frag)
    const unsigned short* __restrict__ b1base = B1_s + (size_t)l * 8;

    // ---- main loop: 8 slabs of 64 j-rows; wave owns rows [w*16, +16) ----
    const size_t rowbase = (size_t)(bbase + w * 16 + m16) * DD;

    #pragma unroll 1
    for (int st = 0; st < 8; ++st) {
        const float* __restrict__ vr = v + rowbase + (size_t)st * 64 * DD;

        float xr[4][8];
        #pragma unroll
        for (int kt = 0; kt < 4; ++kt) {
            *(float4*)&xr[kt][0] = *(const float4*)(vr + kt * 32 + q8);
            *(float4*)&xr[kt][4] = *(const float4*)(vr + kt * 32 + q8 + 4);
        }

        // ======== layer 1: 16 rows x 64 cols, K=128 ========
        f32x4 c[4];
        #pragma unroll
        for (int ot = 0; ot < 4; ++ot) c[ot] = (f32x4){0.f, 0.f, 0.f, 0.f};

        #pragma unroll
        for (int kt = 0; kt < 4; ++kt) {
            // vi slice from LDS (broadcast, conflict-free) - frees 32 VGPRs
            float y8[8];
            *(float4*)&y8[0] = *(const float4*)(vi_s + kt * 32 + q8);
            *(float4*)&y8[4] = *(const float4*)(vi_s + kt * 32 + q8 + 4);
            float d8[8];
            #pragma unroll
            for (int i = 0; i < 8; ++i) d8[i] = fabsf(y8[i] - xr[kt][i]);
            s16x8 ah, al;
            split8(d8, ah, al);                    // 1 split feeds 12 MFMAs
            #pragma unroll
            for (int ot = 0; ot < 4; ++ot) {
                const int f = kt * 4 + ot;
                s16x8 bh = *(const s16x8*)(b1base + (size_t)f * 512);
                s16x8 bl = *(const s16x8*)(b1base + (size_t)(16 + f) * 512);
                c[ot] = MFMA(ah, bh, c[ot]);
                c[ot] = MFMA(al, bh, c[ot]);
                c[ot] = MFMA(ah, bl, c[ot]);
            }
        }

        // bias + leaky -> h1 rows [w*16, +16): wave-private (no barrier)
        #pragma unroll
        for (int ot = 0; ot < 4; ++ot)
            #pragma unroll
            for (int r = 0; r < 4; ++r) {
                float hv = c[ot][r] + b1v[ot];
                hv = fmaxf(hv, 0.1f * hv);
                h1_s[(w * 16 + q * 4 + r) * H1S + ot * 16 + m16] = hv;
            }

        // ======== layer 2: same 16 rows, 32 cols, K=64 (B2 from regs) ========
        f32x4 dacc[2];
        dacc[0] = (f32x4){0.f, 0.f, 0.f, 0.f};
        dacc[1] = (f32x4){0.f, 0.f, 0.f, 0.f};
        #pragma unroll
        for (int kt2 = 0; kt2 < 2; ++kt2) {
            const float* hp = h1_s + (w * 16 + m16) * H1S + kt2 * 32 + q8;
            float a8[8];
            *(float4*)&a8[0] = *(const float4*)(hp);
            *(float4*)&a8[4] = *(const float4*)(hp + 4);
            s16x8 ah, al;
            split8(a8, ah, al);
            #pragma unroll
            for (int ot2 = 0; ot2 < 2; ++ot2) {
                dacc[ot2] = MFMA(ah, B2h[ot2][kt2], dacc[ot2]);
                dacc[ot2] = MFMA(al, B2h[ot2][kt2], dacc[ot2]);
                dacc[ot2] = MFMA(ah, B2l[ot2][kt2], dacc[ot2]);
            }
        }

        // ======== layer 3 + 16-lane reduce -> logits ========
        #pragma unroll
        for (int r = 0; r < 4; ++r) {
            float h0 = dacc[0][r] + b2v0;  h0 = fmaxf(h0, 0.1f * h0);
            float h1v = dacc[1][r] + b2v1; h1v = fmaxf(h1v, 0.1f * h1v);
            float s = fmaf(w3v0, h0, w3v1 * h1v);
            s += __shfl_xor(s, 1, 64);
            s += __shfl_xor(s, 2, 64);
            s += __shfl_xor(s, 4, 64);
            s += __shfl_xor(s, 8, 64);
            if (m16 == 0)
                logits[st * 64 + w * 16 + q * 4 + r] = s + b3v;
        }
    }

    __syncthreads();   // logits complete

    // ---- fused softmax over 512 logits ----
    float a0 = logits[t];
    float a1 = logits[t + 256];

    float m = fmaxf(a0, a1);
    #pragma unroll
    for (int s = 32; s > 0; s >>= 1)
        m = fmaxf(m, __shfl_xor(m, s, 64));
    if (l == 0) red[w] = m;
    __syncthreads();
    const float M = fmaxf(fmaxf(red[0], red[1]), fmaxf(red[2], red[3]));

    float e0 = __expf(a0 - M);
    float e1 = __expf(a1 - M);
    float s01 = e0 + e1;
    #pragma unroll
    for (int s = 32; s > 0; s >>= 1)
        s01 += __shfl_xor(s01, s, 64);
    if (l == 0) red[4 + w] = s01;
    __syncthreads();
    const float S = (red[4] + red[5]) + (red[6] + red[7]);
    const float inv = 1.0f / S;

    float* orow = out + (size_t)blk * NN;
    orow[t]       = e0 * inv;
    orow[t + 256] = e1 * inv;
}

extern "C" void kernel_launch(void* const* d_in, const int* in_sizes, int n_in,
                              void* d_out, int out_size, void* d_ws, size_t ws_size,
                              hipStream_t stream) {
    const float* v  = (const float*)d_in[0];
    const float* W1 = (const float*)d_in[1];
    const float* b1 = (const float*)d_in[2];
    const float* W2 = (const float*)d_in[3];
    const float* b2 = (const float*)d_in[4];
    const float* W3 = (const float*)d_in[5];
    const float* b3 = (const float*)d_in[6];
    float* out = (float*)d_out;

    adj_mfma4<<<dim3(4 * NN), dim3(256), 0, stream>>>(v, W1, b1, W2, b2, W3, b3, out);
}

// Round 7
// 184.198 us; speedup vs baseline: 1.9178x; 1.9178x over previous
//
#include <hip/hip_runtime.h>

#define NN  512
#define DD  128

typedef __attribute__((ext_vector_type(4))) float f32x4;
typedef __attribute__((ext_vector_type(8))) short s16x8;   // 8 bf16 (4 VGPRs)

#define MFMA(a, b, c) __builtin_amdgcn_mfma_f32_16x16x32_bf16((a), (b), (c), 0, 0, 0)

#define H1S 68    // h1 row stride (floats): 64+4 pad -> worst 2-way conflict (free)

// fp32 -> (bf16 hi [RNA], bf16 lo [trunc of exact remainder]), packed via v_perm.
// hh+hl+lh passes capture the product to ~2^-17 rel (ll term <= 2^-18, dropped).
__device__ inline void split8(const float* __restrict__ x, s16x8& h, s16x8& l) {
    uint4 hp, lp;
    unsigned* hw = (unsigned*)&hp;
    unsigned* lw = (unsigned*)&lp;
    #pragma unroll
    for (int i = 0; i < 4; ++i) {
        float x0 = x[2 * i], x1 = x[2 * i + 1];
        unsigned t0 = __float_as_uint(x0) + 0x8000u;
        unsigned t1 = __float_as_uint(x1) + 0x8000u;
        hw[i] = __builtin_amdgcn_perm(t1, t0, 0x07060302u);
        float l0 = x0 - __uint_as_float(t0 & 0xFFFF0000u);
        float l1 = x1 - __uint_as_float(t1 & 0xFFFF0000u);
        lw[i] = __builtin_amdgcn_perm(__float_as_uint(l1), __float_as_uint(l0), 0x07060302u);
    }
    h = __builtin_bit_cast(s16x8, hp);
    l = __builtin_bit_cast(s16x8, lp);
}

// (512,2): the ONLY verified-safe pressure config (r4: 128 VGPR, no spill).
// r5/r6 lesson: min-waves=3 or waves_per_eu attr -> 84-VGPR target -> 600 MB
// of scratch thrash. Occupancy comes from the 8-wave block instead:
// 2 blocks/CU x 8 waves = 16 waves/CU (r4 had 8).
__global__ __launch_bounds__(512, 2)
void adj_mfma5(const float* __restrict__ v,
               const float* __restrict__ W1,
               const float* __restrict__ b1,
               const float* __restrict__ W2,
               const float* __restrict__ b2,
               const float* __restrict__ W3,
               const float* __restrict__ b3,
               float* __restrict__ out)
{
    // 76.6 KB -> 2 blocks/CU. B1_s/B2_s FRAG-MAJOR: lane l's s16x8 of frag
    // slot f lives at (f*64+l)*16 B -> one shared v-addr (l*16), imm offsets,
    // conflict-free, zero addr VALU.
    __shared__ __attribute__((aligned(16))) unsigned short B1_s[32 * 64 * 8];
    __shared__ __attribute__((aligned(16))) unsigned short B2_s[8 * 64 * 8];
    __shared__ __attribute__((aligned(16))) float h1_s[128 * H1S];
    __shared__ __attribute__((aligned(16))) float vi_s[DD];
    __shared__ float logits[NN];
    __shared__ float red[16];

    const int blk   = blockIdx.x;        // b*N + i
    const int t     = threadIdx.x;       // 0..511
    const int w     = t >> 6;            // wave 0..7
    const int l     = t & 63;
    const int m16   = t & 15;
    const int q     = l >> 4;
    const int q8    = q * 8;
    const int bbase = blk & ~(NN - 1);

    // ---- stage v_i ----
    if (t < DD / 4)
        ((float4*)vi_s)[t] = ((const float4*)(v + (size_t)blk * DD))[t];

    // ---- prologue: W1 -> frag-major split LDS (1024 frag-slots / 512 thr) ----
    #pragma unroll
    for (int e = 0; e < 2; ++e) {
        int slot = e * 512 + t;
        int f  = slot >> 6;              // frag 0..15 (kt*4+ot)
        int fl = slot & 63;
        int kt = f >> 2, ot = f & 3;
        int fm = fl & 15, fq = fl >> 4;
        const float* src = W1 + (size_t)(ot * 16 + fm) * DD + kt * 32 + fq * 8;
        float x[8];
        *(float4*)&x[0] = *(const float4*)(src);
        *(float4*)&x[4] = *(const float4*)(src + 4);
        s16x8 h, lo;
        split8(x, h, lo);
        *(s16x8*)(B1_s + (size_t)(f * 64 + fl) * 8)        = h;
        *(s16x8*)(B1_s + (size_t)((16 + f) * 64 + fl) * 8) = lo;
    }
    // ---- W2 -> frag-major split LDS (4 src slots x 64 lanes = 256 thr) ----
    if (t < 256) {
        int f2 = t >> 6;                 // 0..3 = kt2*2+ot2
        int fl = t & 63;
        int kt2 = f2 >> 1, ot2 = f2 & 1;
        int fm = fl & 15, fq = fl >> 4;
        const float* src = W2 + (size_t)(ot2 * 16 + fm) * 64 + kt2 * 32 + fq * 8;
        float x[8];
        *(float4*)&x[0] = *(const float4*)(src);
        *(float4*)&x[4] = *(const float4*)(src + 4);
        s16x8 h, lo;
        split8(x, h, lo);
        *(s16x8*)(B2_s + (size_t)(f2 * 64 + fl) * 8)       = h;
        *(s16x8*)(B2_s + (size_t)((4 + f2) * 64 + fl) * 8) = lo;
    }

    // per-lane constants
    float b1v[4];
    #pragma unroll
    for (int ot = 0; ot < 4; ++ot) b1v[ot] = b1[ot * 16 + m16];
    const float b2v0 = b2[m16];
    const float b2v1 = b2[16 + m16];
    const float w3v0 = W3[m16];
    const float w3v1 = W3[16 + m16];
    const float b3v  = b3[0];

    __syncthreads();   // B1/B2 frags + vi ready

    const unsigned short* __restrict__ b1base = B1_s + (size_t)l * 8;
    const unsigned short* __restrict__ b2base = B2_s + (size_t)l * 8;

    // ---- main loop: 4 slabs of 128 j-rows; wave owns rows [w*16, +16) ----
    const size_t rowbase = (size_t)(bbase + w * 16 + m16) * DD;

    #pragma unroll 1
    for (int st = 0; st < 4; ++st) {
        const float* __restrict__ vr = v + rowbase + (size_t)st * 128 * DD;

        float xr[4][8];
        #pragma unroll
        for (int kt = 0; kt < 4; ++kt) {
            *(float4*)&xr[kt][0] = *(const float4*)(vr + kt * 32 + q8);
            *(float4*)&xr[kt][4] = *(const float4*)(vr + kt * 32 + q8 + 4);
        }

        // ======== layer 1: 16 rows x 64 cols, K=128 ========
        f32x4 c[4];
        #pragma unroll
        for (int ot = 0; ot < 4; ++ot) c[ot] = (f32x4){0.f, 0.f, 0.f, 0.f};

        #pragma unroll
        for (int kt = 0; kt < 4; ++kt) {
            float y8[8];   // vi slice from LDS (broadcast, conflict-free)
            *(float4*)&y8[0] = *(const float4*)(vi_s + kt * 32 + q8);
            *(float4*)&y8[4] = *(const float4*)(vi_s + kt * 32 + q8 + 4);
            float d8[8];
            #pragma unroll
            for (int i = 0; i < 8; ++i) d8[i] = fabsf(y8[i] - xr[kt][i]);
            s16x8 ah, al;
            split8(d8, ah, al);                    // 1 split feeds 12 MFMAs
            #pragma unroll
            for (int ot = 0; ot < 4; ++ot) {
                const int f = kt * 4 + ot;
                s16x8 bh = *(const s16x8*)(b1base + (size_t)f * 512);
                s16x8 bl = *(const s16x8*)(b1base + (size_t)(16 + f) * 512);
                c[ot] = MFMA(ah, bh, c[ot]);
                c[ot] = MFMA(al, bh, c[ot]);
                c[ot] = MFMA(ah, bl, c[ot]);
            }
        }

        // bias + leaky -> h1 rows [w*16, +16): wave-private (no barrier)
        #pragma unroll
        for (int ot = 0; ot < 4; ++ot)
            #pragma unroll
            for (int r = 0; r < 4; ++r) {
                float hv = c[ot][r] + b1v[ot];
                hv = fmaxf(hv, 0.1f * hv);
                h1_s[(w * 16 + q * 4 + r) * H1S + ot * 16 + m16] = hv;
            }

        // ======== layer 2: same 16 rows, 32 cols, K=64 ========
        f32x4 dacc[2];
        dacc[0] = (f32x4){0.f, 0.f, 0.f, 0.f};
        dacc[1] = (f32x4){0.f, 0.f, 0.f, 0.f};
        #pragma unroll
        for (int kt2 = 0; kt2 < 2; ++kt2) {
            const float* hp = h1_s + (w * 16 + m16) * H1S + kt2 * 32 + q8;
            float a8[8];
            *(float4*)&a8[0] = *(const float4*)(hp);
            *(float4*)&a8[4] = *(const float4*)(hp + 4);
            s16x8 ah, al;
            split8(a8, ah, al);
            #pragma unroll
            for (int ot2 = 0; ot2 < 2; ++ot2) {
                const int f2 = kt2 * 2 + ot2;
                s16x8 bh = *(const s16x8*)(b2base + (size_t)f2 * 512);
                s16x8 bl = *(const s16x8*)(b2base + (size_t)(4 + f2) * 512);
                dacc[ot2] = MFMA(ah, bh, dacc[ot2]);
                dacc[ot2] = MFMA(al, bh, dacc[ot2]);
                dacc[ot2] = MFMA(ah, bl, dacc[ot2]);
            }
        }

        // ======== layer 3 + 16-lane reduce -> logits ========
        #pragma unroll
        for (int r = 0; r < 4; ++r) {
            float h0 = dacc[0][r] + b2v0;  h0 = fmaxf(h0, 0.1f * h0);
            float h1v = dacc[1][r] + b2v1; h1v = fmaxf(h1v, 0.1f * h1v);
            float s = fmaf(w3v0, h0, w3v1 * h1v);
            s += __shfl_xor(s, 1, 64);
            s += __shfl_xor(s, 2, 64);
            s += __shfl_xor(s, 4, 64);
            s += __shfl_xor(s, 8, 64);
            if (m16 == 0)
                logits[st * 128 + w * 16 + q * 4 + r] = s + b3v;
        }
    }

    __syncthreads();   // logits complete

    // ---- fused softmax over 512 logits (1 per thread) ----
    float a0 = logits[t];

    float m = a0;
    #pragma unroll
    for (int s = 32; s > 0; s >>= 1)
        m = fmaxf(m, __shfl_xor(m, s, 64));
    if (l == 0) red[w] = m;
    __syncthreads();
    const float M = fmaxf(fmaxf(fmaxf(red[0], red[1]), fmaxf(red[2], red[3])),
                          fmaxf(fmaxf(red[4], red[5]), fmaxf(red[6], red[7])));

    float e0 = __expf(a0 - M);
    float s01 = e0;
    #pragma unroll
    for (int s = 32; s > 0; s >>= 1)
        s01 += __shfl_xor(s01, s, 64);
    if (l == 0) red[8 + w] = s01;
    __syncthreads();
    const float S = ((red[8] + red[9]) + (red[10] + red[11])) +
                    ((red[12] + red[13]) + (red[14] + red[15]));
    const float inv = 1.0f / S;

    out[(size_t)blk * NN + t] = e0 * inv;
}

extern "C" void kernel_launch(void* const* d_in, const int* in_sizes, int n_in,
                              void* d_out, int out_size, void* d_ws, size_t ws_size,
                              hipStream_t stream) {
    const float* v  = (const float*)d_in[0];
    const float* W1 = (const float*)d_in[1];
    const float* b1 = (const float*)d_in[2];
    const float* W2 = (const float*)d_in[3];
    const float* b2 = (const float*)d_in[4];
    const float* W3 = (const float*)d_in[5];
    const float* b3 = (const float*)d_in[6];
    float* out = (float*)d_out;

    adj_mfma5<<<dim3(4 * NN), dim3(512), 0, stream>>>(v, W1, b1, W2, b2, W3, b3, out);
}

// Round 8
// 173.551 us; speedup vs baseline: 2.0355x; 1.0613x over previous
//
#include <hip/hip_runtime.h>

#define NN  512
#define DD  128

typedef __attribute__((ext_vector_type(4))) float f32x4;
typedef __attribute__((ext_vector_type(8))) short s16x8;   // 8 bf16 (4 VGPRs)

#define MFMA(a, b, c) __builtin_amdgcn_mfma_f32_16x16x32_bf16((a), (b), (c), 0, 0, 0)

#define H1S 68    // h1 row stride (floats): 64+4 pad -> worst 2-way conflict (free)

// fp32 -> (bf16 hi [RNA], bf16 lo [trunc of exact remainder]), packed via v_perm.
// hh+hl+lh passes capture the product to ~2^-17 rel (ll term <= 2^-18, dropped).
__device__ inline void split8(const float* __restrict__ x, s16x8& h, s16x8& l) {
    uint4 hp, lp;
    unsigned* hw = (unsigned*)&hp;
    unsigned* lw = (unsigned*)&lp;
    #pragma unroll
    for (int i = 0; i < 4; ++i) {
        float x0 = x[2 * i], x1 = x[2 * i + 1];
        unsigned t0 = __float_as_uint(x0) + 0x8000u;
        unsigned t1 = __float_as_uint(x1) + 0x8000u;
        hw[i] = __builtin_amdgcn_perm(t1, t0, 0x07060302u);
        float l0 = x0 - __uint_as_float(t0 & 0xFFFF0000u);
        float l1 = x1 - __uint_as_float(t1 & 0xFFFF0000u);
        lw[i] = __builtin_amdgcn_perm(__float_as_uint(l1), __float_as_uint(l0), 0x07060302u);
    }
    h = __builtin_bit_cast(s16x8, hp);
    l = __builtin_bit_cast(s16x8, lp);
}

// (256,2): the ONLY verified-safe pressure config (r4: 128 VGPR, zero spill).
// r5/r6 lesson: min-waves=3 / amdgpu_waves_per_eu -> 84-VGPR target -> 600 MB
// scratch thrash.  Occupancy rises via LDS instead: 52.8 KB/block -> 3
// blocks/CU (proven co-schedulable at this size by r5/r6's 30% occupancy)
// = 12 waves/CU vs r4's 8.
__global__ __launch_bounds__(256, 2)
void adj_mfma6(const float* __restrict__ v,
               const float* __restrict__ W1,
               const float* __restrict__ b1,
               const float* __restrict__ W2,
               const float* __restrict__ b2,
               const float* __restrict__ W3,
               const float* __restrict__ b3,
               float* __restrict__ out)
{
    // ~52.8 KB -> 3 blocks/CU.  B1_s FRAG-MAJOR: lane l's s16x8 of frag slot
    // f lives at (f*64+l)*16 B -> one shared v-addr (l*16), imm offsets,
    // conflict-free, zero addr VALU.
    __shared__ __attribute__((aligned(16))) unsigned short B1_s[32 * 64 * 8];
    __shared__ __attribute__((aligned(16))) float h1_s[64 * H1S];
    __shared__ __attribute__((aligned(16))) float vi_s[DD];
    __shared__ float logits[NN];
    __shared__ float red[8];

    const int blk   = blockIdx.x;        // b*N + i
    const int t     = threadIdx.x;
    const int w     = t >> 6;            // wave 0..3
    const int l     = t & 63;
    const int m16   = t & 15;
    const int q     = l >> 4;
    const int q8    = q * 8;
    const int bbase = blk & ~(NN - 1);

    // ---- stage v_i (128 floats) ----
    if (t < DD / 4)
        ((float4*)vi_s)[t] = ((const float4*)(v + (size_t)blk * DD))[t];

    // ---- prologue: W1 -> frag-major split LDS (1024 frag-slots / 256 thr) ----
    #pragma unroll
    for (int e = 0; e < 4; ++e) {
        int slot = e * 256 + t;
        int f  = slot >> 6;              // frag 0..15 (kt*4+ot)
        int fl = slot & 63;              // lane within frag
        int kt = f >> 2, ot = f & 3;
        int fm = fl & 15, fq = fl >> 4;
        const float* src = W1 + (size_t)(ot * 16 + fm) * DD + kt * 32 + fq * 8;
        float x[8];
        *(float4*)&x[0] = *(const float4*)(src);
        *(float4*)&x[4] = *(const float4*)(src + 4);
        s16x8 h, lo;
        split8(x, h, lo);
        *(s16x8*)(B1_s + (size_t)(f * 64 + fl) * 8)        = h;
        *(s16x8*)(B1_s + (size_t)((16 + f) * 64 + fl) * 8) = lo;
    }

    // ---- B2 frags in registers (32 VGPRs; identical in every wave) ----
    s16x8 B2h[2][2], B2l[2][2];
    #pragma unroll
    for (int ot2 = 0; ot2 < 2; ++ot2)
        #pragma unroll
        for (int kt2 = 0; kt2 < 2; ++kt2) {
            const float* src = W2 + (size_t)(ot2 * 16 + m16) * 64 + kt2 * 32 + q8;
            float x[8];
            *(float4*)&x[0] = *(const float4*)(src);
            *(float4*)&x[4] = *(const float4*)(src + 4);
            split8(x, B2h[ot2][kt2], B2l[ot2][kt2]);
        }

    // per-lane constants
    float b1v[4];
    #pragma unroll
    for (int ot = 0; ot < 4; ++ot) b1v[ot] = b1[ot * 16 + m16];
    const float b2v0 = b2[m16];
    const float b2v1 = b2[16 + m16];
    const float w3v0 = W3[m16];
    const float w3v1 = W3[16 + m16];
    const float b3v  = b3[0];

    __syncthreads();   // B1 frags + vi ready

    // shared LDS read base for all B1 frag reads (imm offsets select frag)
    const unsigned short* __restrict__ b1base = B1_s + (size_t)l * 8;

    // ---- main loop: 8 slabs of 64 j-rows; wave owns rows [w*16, +16) ----
    const size_t rowbase = (size_t)(bbase + w * 16 + m16) * DD;

    #pragma unroll 1
    for (int st = 0; st < 8; ++st) {
        const float* __restrict__ vr = v + rowbase + (size_t)st * 64 * DD;

        float xr[4][8];
        #pragma unroll
        for (int kt = 0; kt < 4; ++kt) {
            *(float4*)&xr[kt][0] = *(const float4*)(vr + kt * 32 + q8);
            *(float4*)&xr[kt][4] = *(const float4*)(vr + kt * 32 + q8 + 4);
        }

        // ======== layer 1: 16 rows x 64 cols, K=128 ========
        f32x4 c[4];
        #pragma unroll
        for (int ot = 0; ot < 4; ++ot) c[ot] = (f32x4){0.f, 0.f, 0.f, 0.f};

        #pragma unroll
        for (int kt = 0; kt < 4; ++kt) {
            float y8[8];   // vi slice from LDS (broadcast, conflict-free)
            *(float4*)&y8[0] = *(const float4*)(vi_s + kt * 32 + q8);
            *(float4*)&y8[4] = *(const float4*)(vi_s + kt * 32 + q8 + 4);
            float d8[8];
            #pragma unroll
            for (int i = 0; i < 8; ++i) d8[i] = fabsf(y8[i] - xr[kt][i]);
            s16x8 ah, al;
            split8(d8, ah, al);                    // 1 split feeds 12 MFMAs
            #pragma unroll
            for (int ot = 0; ot < 4; ++ot) {
                const int f = kt * 4 + ot;
                s16x8 bh = *(const s16x8*)(b1base + (size_t)f * 512);
                s16x8 bl = *(const s16x8*)(b1base + (size_t)(16 + f) * 512);
                c[ot] = MFMA(ah, bh, c[ot]);
                c[ot] = MFMA(al, bh, c[ot]);
                c[ot] = MFMA(ah, bl, c[ot]);
            }
        }

        // bias + leaky -> h1 rows [w*16, +16): wave-private (no barrier)
        #pragma unroll
        for (int ot = 0; ot < 4; ++ot)
            #pragma unroll
            for (int r = 0; r < 4; ++r) {
                float hv = c[ot][r] + b1v[ot];
                hv = fmaxf(hv, 0.1f * hv);
                h1_s[(w * 16 + q * 4 + r) * H1S + ot * 16 + m16] = hv;
            }

        // ======== layer 2: same 16 rows, 32 cols, K=64 (B2 from regs) ========
        f32x4 dacc[2];
        dacc[0] = (f32x4){0.f, 0.f, 0.f, 0.f};
        dacc[1] = (f32x4){0.f, 0.f, 0.f, 0.f};
        #pragma unroll
        for (int kt2 = 0; kt2 < 2; ++kt2) {
            const float* hp = h1_s + (w * 16 + m16) * H1S + kt2 * 32 + q8;
            float a8[8];
            *(float4*)&a8[0] = *(const float4*)(hp);
            *(float4*)&a8[4] = *(const float4*)(hp + 4);
            s16x8 ah, al;
            split8(a8, ah, al);
            #pragma unroll
            for (int ot2 = 0; ot2 < 2; ++ot2) {
                dacc[ot2] = MFMA(ah, B2h[ot2][kt2], dacc[ot2]);
                dacc[ot2] = MFMA(al, B2h[ot2][kt2], dacc[ot2]);
                dacc[ot2] = MFMA(ah, B2l[ot2][kt2], dacc[ot2]);
            }
        }

        // ======== layer 3 + 16-lane reduce -> logits ========
        #pragma unroll
        for (int r = 0; r < 4; ++r) {
            float h0 = dacc[0][r] + b2v0;  h0 = fmaxf(h0, 0.1f * h0);
            float h1v = dacc[1][r] + b2v1; h1v = fmaxf(h1v, 0.1f * h1v);
            float s = fmaf(w3v0, h0, w3v1 * h1v);
            s += __shfl_xor(s, 1, 64);
            s += __shfl_xor(s, 2, 64);
            s += __shfl_xor(s, 4, 64);
            s += __shfl_xor(s, 8, 64);
            if (m16 == 0)
                logits[st * 64 + w * 16 + q * 4 + r] = s + b3v;
        }
    }

    __syncthreads();   // logits complete

    // ---- fused softmax over 512 logits (2 per thread) ----
    float a0 = logits[t];
    float a1 = logits[t + 256];

    float m = fmaxf(a0, a1);
    #pragma unroll
    for (int s = 32; s > 0; s >>= 1)
        m = fmaxf(m, __shfl_xor(m, s, 64));
    if (l == 0) red[w] = m;
    __syncthreads();
    const float M = fmaxf(fmaxf(red[0], red[1]), fmaxf(red[2], red[3]));

    float e0 = __expf(a0 - M);
    float e1 = __expf(a1 - M);
    float s01 = e0 + e1;
    #pragma unroll
    for (int s = 32; s > 0; s >>= 1)
        s01 += __shfl_xor(s01, s, 64);
    if (l == 0) red[4 + w] = s01;
    __syncthreads();
    const float S = (red[4] + red[5]) + (red[6] + red[7]);
    const float inv = 1.0f / S;

    float* orow = out + (size_t)blk * NN;
    orow[t]       = e0 * inv;
    orow[t + 256] = e1 * inv;
}

extern "C" void kernel_launch(void* const* d_in, const int* in_sizes, int n_in,
                              void* d_out, int out_size, void* d_ws, size_t ws_size,
                              hipStream_t stream) {
    const float* v  = (const float*)d_in[0];
    const float* W1 = (const float*)d_in[1];
    const float* b1 = (const float*)d_in[2];
    const float* W2 = (const float*)d_in[3];
    const float* b2 = (const float*)d_in[4];
    const float* W3 = (const float*)d_in[5];
    const float* b3 = (const float*)d_in[6];
    float* out = (float*)d_out;

    adj_mfma6<<<dim3(4 * NN), dim3(256), 0, stream>>>(v, W1, b1, W2, b2, W3, b3, out);
}